// Round 13
// baseline (402.027 us; speedup 1.0000x reference)
//
#include <hip/hip_runtime.h>

// ---- problem constants ----
#define SRAD 3
#define TRAD 1
#define Hdim 256
#define Wdim 256
#define Tdim 32
#define CS (Hdim*Wdim*Tdim)

// ---- tiling: 8x8x8 tile, 1 output/thread, 2 blocks/CU ----
#define TH 8
#define TW 8
#define TT 8
#define HS (TH + 2*SRAD)      // 14
#define WS (TW + 2*SRAD)      // 14
#define TSZ (TT + 2*TRAD)     // 10 real t-px per row
#define RS 11                 // padded row stride -> near-uniform bank residues
#define NROWS (HS*WS)         // 196
#define NPX (NROWS*TSZ)       // 1960 real px
#define NSLOT (NROWS*RS)      // 2156 padded slots
#define NTHREADS 1024
#define NSUB 2
#define NCOL 512              // output px per tile

// LDS planes (dword offsets), per px slot (9 dwords = 36 B):
//   AG [NSLOT][4] : (g0,g1)(g2,g3)(g4,g5)(g6,g7)  fp16 pairs, sqrt(sigma*log2e)-scaled
//   EVN[NSLOT][4] : (e0',e1')(v0,v1)(e2',v2)(n0,n1) fp16 pairs, e' = e/gamma
//   X  [NSLOT][1] : (g8,n2) fp16 pair
#define EVN_OFF (4*NSLOT)
#define X_OFF   (8*NSLOT)
#define SMEM_BYTES (9*NSLOT*4)   // 77,616 B -> 2 blocks/CU with VGPR <= 32

typedef _Float16 half2_t __attribute__((ext_vector_type(2)));

#if defined(__has_builtin)
#if __has_builtin(__builtin_amdgcn_exp2f)
#define EXPW(x) __builtin_amdgcn_exp2f(x)
#define LOG2E_SC 1.4426950408889634f
#else
#define EXPW(x) __expf(x)
#define LOG2E_SC 1.0f
#endif
#if __has_builtin(__builtin_elementwise_fma)
#define PKFMA(a, b, c) __builtin_elementwise_fma((a), (b), (c))
#else
#define PKFMA(a, b, c) ((a) * (b) + (c))
#endif
#if __has_builtin(__builtin_fminf16)
#define HMIN(a, b) __builtin_fminf16((a), (b))
#else
#define HMIN(a, b) ((a) < (b) ? (a) : (b))
#endif
#else
#define EXPW(x) __expf(x)
#define LOG2E_SC 1.0f
#define PKFMA(a, b, c) ((a) * (b) + (c))
#define HMIN(a, b) ((a) < (b) ? (a) : (b))
#endif

#define INVG 0.343100187f   // 1 / 2.9146

static __device__ __forceinline__ unsigned pack_h2(float a, float b) {
    return __builtin_bit_cast(unsigned, __builtin_amdgcn_cvt_pkrtz(a, b));
}
static __device__ __forceinline__ half2_t h2(unsigned u) {
    return __builtin_bit_cast(half2_t, u);
}

__global__ __launch_bounds__(NTHREADS, 8) void statden_kernel(
    const float* __restrict__ noisy, const float* __restrict__ guidance,
    const float* __restrict__ est, const float* __restrict__ var,
    const float* __restrict__ sigma_inv, float* __restrict__ out)
{
    extern __shared__ unsigned char smem[];
    unsigned* agP  = (unsigned*)smem;
    unsigned* evnP = agP + EVN_OFF;
    unsigned* xP   = agP + X_OFF;

    const int tid = threadIdx.x;
    const int pix = tid & (NCOL - 1);
    const int sub = tid >> 9;            // 2-way checkerboard split (8-wave-uniform)
    const int h0 = blockIdx.y * TH;
    const int w0 = blockIdx.x * TW;
    const int t0 = blockIdx.z * TT;

    float sq[9];
    #pragma unroll
    for (int c = 0; c < 9; ++c) sq[c] = sqrtf(sigma_inv[c] * LOG2E_SC);

    // ---- stage halo (zero-fill OOB == reference zero padding) ----
    for (int p = tid; p < NPX; p += NTHREADS) {
        int row = p / TSZ;
        int t   = p - row * TSZ;
        int pw  = row % WS;
        int ph  = row / WS;
        int h = h0 - SRAD + ph;
        int w = w0 - SRAD + pw;
        int tg = t0 - TRAD + t;
        bool ok = ((unsigned)h < (unsigned)Hdim) && ((unsigned)w < (unsigned)Wdim)
               && ((unsigned)tg < (unsigned)Tdim);
        int base = (h * Wdim + w) * Tdim + tg;

        float g[9];
        #pragma unroll
        for (int c = 0; c < 9; ++c) g[c] = ok ? guidance[c*CS + base] * sq[c] : 0.f;
        float e0 = ok ? est[0*CS + base] * INVG : 0.f;
        float e1 = ok ? est[1*CS + base] * INVG : 0.f;
        float e2 = ok ? est[2*CS + base] * INVG : 0.f;
        float v0 = ok ? var[0*CS + base] : 0.f;
        float v1 = ok ? var[1*CS + base] : 0.f;
        float v2 = ok ? var[2*CS + base] : 0.f;
        float n0 = ok ? noisy[0*CS + base] : 0.f;
        float n1 = ok ? noisy[1*CS + base] : 0.f;
        float n2 = ok ? noisy[2*CS + base] : 0.f;

        const int idx = row * RS + t;
        uint4 ag;
        ag.x = pack_h2(g[0], g[1]); ag.y = pack_h2(g[2], g[3]);
        ag.z = pack_h2(g[4], g[5]); ag.w = pack_h2(g[6], g[7]);
        *(uint4*)(agP + 4*idx) = ag;
        uint4 ev;
        ev.x = pack_h2(e0, e1); ev.y = pack_h2(v0, v1);
        ev.z = pack_h2(e2, v2); ev.w = pack_h2(n0, n1);
        *(uint4*)(evnP + 4*idx) = ev;
        xP[idx] = pack_h2(g[8], n2);
    }
    __syncthreads();

    // ---- per-thread single output px ----
    const int tt = pix & 7;
    const int ww = (pix >> 3) & 7;
    const int hh = pix >> 6;
    const int crow = (hh + SRAD) * WS + (ww + SRAD);
    const int cidx = crow * RS + tt;    // window slot for tp=0 (dt=-1)

    // center terms (center lives at slot cidx+1)
    half2_t agx0, agx1, agx2, agx3;
    _Float16 cgx8;
    half2_t ex01, vx01, cx2m;
    {
        const int ci = cidx + 1;
        uint4 cag = *(const uint4*)(agP + 4*ci);
        agx0 = h2(cag.x); agx1 = h2(cag.y);
        agx2 = h2(cag.z); agx3 = h2(cag.w);
        cgx8 = h2(xP[ci]).x;
        uint4 cev = *(const uint4*)(evnP + 4*ci);
        ex01 = h2(cev.x);
        vx01 = h2(cev.y);
        cx2m = h2(cev.z ^ 0x00008000u);   // negate e2'
    }

    float nm0 = 0.f, nm1 = 0.f, nm2 = 0.f, den = 0.f;

#define EVAL1(A, E, XQ) do {                                             \
    /* guidance: acc = -sum of squared f16 diffs (8ch packed + g8 scalar) */ \
    half2_t acc = (half2_t){(_Float16)0, (_Float16)0};                   \
    half2_t d;                                                           \
    d = h2(A.x) - agx0; acc = PKFMA(-d, d, acc);                         \
    d = h2(A.y) - agx1; acc = PKFMA(-d, d, acc);                         \
    d = h2(A.z) - agx2; acc = PKFMA(-d, d, acc);                         \
    d = h2(A.w) - agx3; acc = PKFMA(-d, d, acc);                         \
    const _Float16 d8 = h2(XQ).x - cgx8;                                 \
    _Float16 sa = acc.x + acc.y;                                         \
    sa = __builtin_fmaf16(-d8, d8, sa);                                  \
    const float wjf = EXPW((float)sa);                                   \
    /* packed t-test: vs - de^2 >= 0 per channel (e' = e/gamma) */       \
    const half2_t de01 = h2(E.x) - ex01;                                 \
    const half2_t vs01 = h2(E.y) + vx01;                                 \
    const half2_t m01  = PKFMA(-de01, de01, vs01);                       \
    const half2_t s2   = h2(E.z) + cx2m;                                 \
    const _Float16 m2v = __builtin_fmaf16(-s2.x, s2.x, s2.y);            \
    const _Float16 mn  = HMIN(HMIN(m01.x, m01.y), m2v);                  \
    const float wgt = (mn >= (_Float16)0) ? wjf : 0.f;                   \
    nm0 = __builtin_fmaf(wgt, (float)h2(E.w).x, nm0);                    \
    nm1 = __builtin_fmaf(wgt, (float)h2(E.w).y, nm1);                    \
    nm2 = __builtin_fmaf(wgt, (float)h2(XQ).y,  nm2);                    \
    den += wgt;                                                          \
} while (0)

    #pragma unroll 1
    for (int dh = 0; dh < 7; ++dh) {
        #pragma unroll 1
        for (int dw = ((dh + sub) & 1); dw < 7; dw += 2) {
            const int nbase = cidx + ((dh - SRAD) * WS + (dw - SRAD)) * RS;

            #pragma unroll
            for (int tp = 0; tp < 3; ++tp) {
                const int ni = nbase + tp;
                const uint4 a    = *(const uint4*)(agP + 4*ni);
                const unsigned q = xP[ni];
                const uint4 e    = *(const uint4*)(evnP + 4*ni);
                EVAL1(a, e, q);
            }
        }
    }

    // ---- combine 2 checkerboard partials via LDS ----
    __syncthreads();
    float* red = (float*)smem;   // 512 * 4 * 4 B = 8 KB, reuse staged region
    if (sub == 1) {
        float4 v; v.x = nm0; v.y = nm1; v.z = nm2; v.w = den;
        *(float4*)(red + 4 * pix) = v;
    }
    __syncthreads();
    if (sub == 0) {
        float4 v = *(const float4*)(red + 4 * pix);
        nm0 += v.x; nm1 += v.y; nm2 += v.z; den += v.w;
        const float inv = 1.0f / (den + 1e-10f);

        const int hG = h0 + hh, wG = w0 + ww;
        const int ob = (hG * Wdim + wG) * Tdim + t0 + tt;
        out[0*CS + ob] = nm0 * inv;
        out[1*CS + ob] = nm1 * inv;
        out[2*CS + ob] = nm2 * inv;
    }
}

extern "C" void kernel_launch(void* const* d_in, const int* in_sizes, int n_in,
                              void* d_out, int out_size, void* d_ws, size_t ws_size,
                              hipStream_t stream) {
    const float* noisy    = (const float*)d_in[0];
    const float* guidance = (const float*)d_in[1];
    const float* est      = (const float*)d_in[2];
    const float* var      = (const float*)d_in[3];
    const float* sig      = (const float*)d_in[4];
    float* out = (float*)d_out;

    (void)in_sizes; (void)n_in; (void)out_size; (void)d_ws; (void)ws_size;

    (void)hipFuncSetAttribute(reinterpret_cast<const void*>(statden_kernel),
                              hipFuncAttributeMaxDynamicSharedMemorySize, SMEM_BYTES);

    dim3 grid(Wdim / TW, Hdim / TH, Tdim / TT);   // (32, 32, 4)
    statden_kernel<<<grid, NTHREADS, SMEM_BYTES, stream>>>(noisy, guidance, est, var, sig, out);
}

// Round 14
// 290.049 us; speedup vs baseline: 1.3861x; 1.3861x over previous
//
#include <hip/hip_runtime.h>

// ---- problem constants ----
#define SRAD 3
#define TRAD 1
#define Hdim 256
#define Wdim 256
#define Tdim 32
#define CS (Hdim*Wdim*Tdim)

// ---- tiling: 8x8x8 tile, 1 output/thread, 2 blocks/CU ----
#define TH 8
#define TW 8
#define TT 8
#define HS (TH + 2*SRAD)      // 14
#define WS (TW + 2*SRAD)      // 14
#define TSZ (TT + 2*TRAD)     // 10 real t-px per row
#define RS 10                 // == TSZ: bank-uniform for 1-output lane layout (tt spans 0..7)
#define NROWS (HS*WS)         // 196
#define NPX (NROWS*TSZ)       // 1960
#define NSLOT NPX             // 1960 (no pad slots)
#define NTHREADS 1024
#define NSUB 2
#define NCOL 512              // output px per tile

// LDS planes (dword offsets), per px slot (10 dwords = 40 B):
//   AG [NSLOT][4] : (g0,g1)(g2,g3)(g4,g5)(g6,g7)  fp16 pairs, sqrt(sigma*log2e)-scaled
//   EVN[NSLOT][4] : (e0',e1')(v0,v1)(e2',v2)(n0,n1) fp16 pairs, e' = e/gamma
//   X2 [NSLOT][2] : (g8,n2) fp16 pair | S f32 (S = scaled-g self-dot, eval-chain order)
#define EVN_OFF (4*NSLOT)
#define X2_OFF  (8*NSLOT)
#define SMEM_BYTES (10*NSLOT*4)  // 78,400 B -> 2 blocks/CU

// skip threshold: weights below 2^-25 are invisible (den >= 1 always)
#define SKIP_ND (-25.0f)

typedef _Float16 half2_t __attribute__((ext_vector_type(2)));

#if defined(__has_builtin)
#if __has_builtin(__builtin_amdgcn_fdot2)
#define HAVE_FDOT2 1
#else
#define HAVE_FDOT2 0
#endif
#if __has_builtin(__builtin_amdgcn_exp2f)
#define EXPW(x) __builtin_amdgcn_exp2f(x)
#define LOG2E_SC 1.4426950408889634f
#else
#define EXPW(x) __expf(x)
#define LOG2E_SC 1.0f
#endif
#if __has_builtin(__builtin_elementwise_fma)
#define PKFMA(a, b, c) __builtin_elementwise_fma((a), (b), (c))
#else
#define PKFMA(a, b, c) ((a) * (b) + (c))
#endif
#if __has_builtin(__builtin_fminf16)
#define HMIN(a, b) __builtin_fminf16((a), (b))
#else
#define HMIN(a, b) ((a) < (b) ? (a) : (b))
#endif
#else
#define HAVE_FDOT2 0
#define EXPW(x) __expf(x)
#define LOG2E_SC 1.0f
#define PKFMA(a, b, c) ((a) * (b) + (c))
#define HMIN(a, b) ((a) < (b) ? (a) : (b))
#endif

#define INVG 0.343100187f   // 1 / 2.9146

static __device__ __forceinline__ unsigned pack_h2(float a, float b) {
    return __builtin_bit_cast(unsigned, __builtin_amdgcn_cvt_pkrtz(a, b));
}
static __device__ __forceinline__ half2_t h2(unsigned u) {
    return __builtin_bit_cast(half2_t, u);
}
// acc += y . x over the 2 fp16 lanes (v_dot2_f32_f16)
static __device__ __forceinline__ float dot2p(unsigned y, half2_t x, float acc) {
#if HAVE_FDOT2
    return __builtin_amdgcn_fdot2(h2(y), x, acc, false);
#else
    half2_t yv = h2(y);
    acc = __builtin_fmaf((float)yv.x, (float)x.x, acc);
    acc = __builtin_fmaf((float)yv.y, (float)x.y, acc);
    return acc;
#endif
}
static __device__ __forceinline__ float dot2s(unsigned y, unsigned x, float acc) {
    return dot2p(y, h2(x), acc);
}

__global__ __launch_bounds__(NTHREADS, 8) void statden_kernel(
    const float* __restrict__ noisy, const float* __restrict__ guidance,
    const float* __restrict__ est, const float* __restrict__ var,
    const float* __restrict__ sigma_inv, float* __restrict__ out)
{
    extern __shared__ unsigned char smem[];
    unsigned* agP  = (unsigned*)smem;
    unsigned* evnP = agP + EVN_OFF;
    unsigned* x2P  = agP + X2_OFF;

    const int tid = threadIdx.x;
    const int pix = tid & (NCOL - 1);
    const int sub = tid >> 9;            // 2-way checkerboard split (8-wave-uniform)
    const int h0 = blockIdx.y * TH;
    const int w0 = blockIdx.x * TW;
    const int t0 = blockIdx.z * TT;

    float sq[9];
    #pragma unroll
    for (int c = 0; c < 9; ++c) sq[c] = sqrtf(sigma_inv[c] * LOG2E_SC);

    // ---- stage halo (zero-fill OOB == reference zero padding) ----
    for (int p = tid; p < NPX; p += NTHREADS) {
        int row = p / TSZ;
        int t   = p - row * TSZ;
        int pw  = row % WS;
        int ph  = row / WS;
        int h = h0 - SRAD + ph;
        int w = w0 - SRAD + pw;
        int tg = t0 - TRAD + t;
        bool ok = ((unsigned)h < (unsigned)Hdim) && ((unsigned)w < (unsigned)Wdim)
               && ((unsigned)tg < (unsigned)Tdim);
        int base = (h * Wdim + w) * Tdim + tg;

        float g[9];
        #pragma unroll
        for (int c = 0; c < 9; ++c) g[c] = ok ? guidance[c*CS + base] * sq[c] : 0.f;
        float e0 = ok ? est[0*CS + base] * INVG : 0.f;
        float e1 = ok ? est[1*CS + base] * INVG : 0.f;
        float e2 = ok ? est[2*CS + base] * INVG : 0.f;
        float v0 = ok ? var[0*CS + base] : 0.f;
        float v1 = ok ? var[1*CS + base] : 0.f;
        float v2 = ok ? var[2*CS + base] : 0.f;
        float n0 = ok ? noisy[0*CS + base] : 0.f;
        float n1 = ok ? noisy[1*CS + base] : 0.f;
        float n2 = ok ? noisy[2*CS + base] : 0.f;

        // slot index == linear p (RS == TSZ, no padding)
        uint4 ag;
        ag.x = pack_h2(g[0], g[1]); ag.y = pack_h2(g[2], g[3]);
        ag.z = pack_h2(g[4], g[5]); ag.w = pack_h2(g[6], g[7]);
        *(uint4*)(agP + 4*p) = ag;
        uint4 ev;
        ev.x = pack_h2(e0, e1); ev.y = pack_h2(v0, v1);
        ev.z = pack_h2(e2, v2); ev.w = pack_h2(n0, n1);
        *(uint4*)(evnP + 4*p) = ev;
        unsigned xq = pack_h2(g[8], n2);
        // S from PACKED values, identical chain order as eval dot -> center dist == 0
        half2_t x8 = h2(xq);
        float S = __builtin_fmaf((float)x8.x, (float)x8.x, 0.f);
        S = dot2s(ag.x, ag.x, S);
        S = dot2s(ag.y, ag.y, S);
        S = dot2s(ag.z, ag.z, S);
        S = dot2s(ag.w, ag.w, S);
        uint2 x2; x2.x = xq; x2.y = __builtin_bit_cast(unsigned, S);
        *(uint2*)(x2P + 2*p) = x2;
    }
    __syncthreads();

    // ---- per-thread single output px ----
    const int tt = pix & 7;
    const int ww = (pix >> 3) & 7;
    const int hh = pix >> 6;
    const int crow = (hh + SRAD) * WS + (ww + SRAD);
    const int cidx = crow * RS + tt;    // window slot for tp=0 (dt=-1)

    // center terms (center lives at slot cidx+1)
    half2_t agx0, agx1, agx2, agx3;
    float cgxf, Sx;
    half2_t ex01, vx01, cx2m;
    {
        const int ci = cidx + 1;
        uint4 cag = *(const uint4*)(agP + 4*ci);
        agx0 = h2(cag.x); agx1 = h2(cag.y);
        agx2 = h2(cag.z); agx3 = h2(cag.w);
        uint2 cx2 = *(const uint2*)(x2P + 2*ci);
        cgxf = (float)h2(cx2.x).x;
        Sx   = __builtin_bit_cast(float, cx2.y);
        uint4 cev = *(const uint4*)(evnP + 4*ci);
        ex01 = h2(cev.x);
        vx01 = h2(cev.y);
        cx2m = h2(cev.z ^ 0x00008000u);   // negate e2'
    }

    float nm0 = 0.f, nm1 = 0.f, nm2 = 0.f, den = 0.f;

    #pragma unroll 1
    for (int dh = 0; dh < 7; ++dh) {
        #pragma unroll 1
        for (int dw = ((dh + sub) & 1); dw < 7; dw += 2) {
            const int nbase = cidx + ((dh - SRAD) * WS + (dw - SRAD)) * RS;

            #pragma unroll
            for (int tp = 0; tp < 3; ++tp) {
                const int ni = nbase + tp;
                const uint4 a  = *(const uint4*)(agP + 4*ni);
                const uint2 x2 = *(const uint2*)(x2P + 2*ni);
                const float Sy = __builtin_bit_cast(float, x2.y);

                // guidance: nd = -(Sy + Sx - 2*dot)  (log2-scaled)
                float dot = __builtin_fmaf((float)h2(x2.x).x, cgxf, 0.f);
                dot = dot2p(a.x, agx0, dot);
                dot = dot2p(a.y, agx1, dot);
                dot = dot2p(a.z, agx2, dot);
                dot = dot2p(a.w, agx3, dot);
                const float ssum = Sy + Sx;
                const float nd = __builtin_fmaf(2.0f, dot, -ssum);   // = -dist

                // wave vote: any lane with non-negligible weight? (den >= 1 always,
                // so weights < 2^-25 are invisible in the output)
                const unsigned long long vote = __ballot(nd >= SKIP_ND);
                if (vote != 0ull) {
                    const uint4 e = *(const uint4*)(evnP + 4*ni);
                    const float wjf = EXPW(nd);

                    // packed t-test: vs - de^2 >= 0 per channel (e' = e/gamma)
                    const half2_t de01 = h2(e.x) - ex01;
                    const half2_t vs01 = h2(e.y) + vx01;
                    const half2_t m01  = PKFMA(-de01, de01, vs01);
                    const half2_t s2   = h2(e.z) + cx2m;
                    const _Float16 m2v = __builtin_fmaf16(-s2.x, s2.x, s2.y);
                    const _Float16 mn  = HMIN(HMIN(m01.x, m01.y), m2v);
                    const float wgt = (mn >= (_Float16)0) ? wjf : 0.f;

                    nm0 = __builtin_fmaf(wgt, (float)h2(e.w).x, nm0);
                    nm1 = __builtin_fmaf(wgt, (float)h2(e.w).y, nm1);
                    nm2 = __builtin_fmaf(wgt, (float)h2(x2.x).y, nm2);
                    den += wgt;
                }
            }
        }
    }

    // ---- combine 2 checkerboard partials via LDS ----
    __syncthreads();
    float* red = (float*)smem;   // 512 * 4 * 4 B = 8 KB, reuse staged region
    if (sub == 1) {
        float4 v; v.x = nm0; v.y = nm1; v.z = nm2; v.w = den;
        *(float4*)(red + 4 * pix) = v;
    }
    __syncthreads();
    if (sub == 0) {
        float4 v = *(const float4*)(red + 4 * pix);
        nm0 += v.x; nm1 += v.y; nm2 += v.z; den += v.w;
        const float inv = 1.0f / (den + 1e-10f);

        const int hG = h0 + hh, wG = w0 + ww;
        const int ob = (hG * Wdim + wG) * Tdim + t0 + tt;
        out[0*CS + ob] = nm0 * inv;
        out[1*CS + ob] = nm1 * inv;
        out[2*CS + ob] = nm2 * inv;
    }
}

extern "C" void kernel_launch(void* const* d_in, const int* in_sizes, int n_in,
                              void* d_out, int out_size, void* d_ws, size_t ws_size,
                              hipStream_t stream) {
    const float* noisy    = (const float*)d_in[0];
    const float* guidance = (const float*)d_in[1];
    const float* est      = (const float*)d_in[2];
    const float* var      = (const float*)d_in[3];
    const float* sig      = (const float*)d_in[4];
    float* out = (float*)d_out;

    (void)in_sizes; (void)n_in; (void)out_size; (void)d_ws; (void)ws_size;

    (void)hipFuncSetAttribute(reinterpret_cast<const void*>(statden_kernel),
                              hipFuncAttributeMaxDynamicSharedMemorySize, SMEM_BYTES);

    dim3 grid(Wdim / TW, Hdim / TH, Tdim / TT);   // (32, 32, 4)
    statden_kernel<<<grid, NTHREADS, SMEM_BYTES, stream>>>(noisy, guidance, est, var, sig, out);
}

// Round 15
// 283.431 us; speedup vs baseline: 1.4184x; 1.0234x over previous
//
#include <hip/hip_runtime.h>

// ---- problem constants ----
#define SRAD 3
#define TRAD 1
#define Hdim 256
#define Wdim 256
#define Tdim 32
#define CS (Hdim*Wdim*Tdim)

// ---- tiling: 8x8x8 tile, 1 output/thread, 2 blocks/CU ----
#define TH 8
#define TW 8
#define TT 8
#define HS (TH + 2*SRAD)      // 14
#define WS (TW + 2*SRAD)      // 14
#define TSZ (TT + 2*TRAD)     // 10 real t-px per row
#define RS 10                 // == TSZ: bank-uniform for 1-output lane layout (tt spans 0..7)
#define NROWS (HS*WS)         // 196
#define NPX (NROWS*TSZ)       // 1960
#define NSLOT NPX             // 1960 (no pad slots)
#define NTHREADS 1024
#define NSUB 2
#define NCOL 512              // output px per tile

// LDS planes (dword offsets), per px slot (10 dwords = 40 B):
//   AG [NSLOT][4] : (g0,g1)(g2,g3)(g4,g5)(g6,g7)  fp16 pairs, sqrt(sigma*log2e)-scaled
//   EVN[NSLOT][4] : (e0',e1')(v0,v1)(e2',v2)(n0,n1) fp16 pairs, e' = e/gamma
//   X2 [NSLOT][2] : (g8,n2) fp16 pair | S f32 (S = scaled-g self-dot, eval-chain order)
#define EVN_OFF (4*NSLOT)
#define X2_OFF  (8*NSLOT)
#define SMEM_BYTES (10*NSLOT*4)  // 78,400 B -> 2 blocks/CU

// skip threshold: den >= 1 always (center weight == 1 exactly), so dropped
// weights <= 2^-16 perturb the output by <= 146 * 2^-16 * |n|max ~ 0.012 worst-case
#define SKIP_ND (-16.0f)

typedef _Float16 half2_t __attribute__((ext_vector_type(2)));

#if defined(__has_builtin)
#if __has_builtin(__builtin_amdgcn_fdot2)
#define HAVE_FDOT2 1
#else
#define HAVE_FDOT2 0
#endif
#if __has_builtin(__builtin_amdgcn_exp2f)
#define EXPW(x) __builtin_amdgcn_exp2f(x)
#define LOG2E_SC 1.4426950408889634f
#else
#define EXPW(x) __expf(x)
#define LOG2E_SC 1.0f
#endif
#if __has_builtin(__builtin_elementwise_fma)
#define PKFMA(a, b, c) __builtin_elementwise_fma((a), (b), (c))
#else
#define PKFMA(a, b, c) ((a) * (b) + (c))
#endif
#if __has_builtin(__builtin_fminf16)
#define HMIN(a, b) __builtin_fminf16((a), (b))
#else
#define HMIN(a, b) ((a) < (b) ? (a) : (b))
#endif
#else
#define HAVE_FDOT2 0
#define EXPW(x) __expf(x)
#define LOG2E_SC 1.0f
#define PKFMA(a, b, c) ((a) * (b) + (c))
#define HMIN(a, b) ((a) < (b) ? (a) : (b))
#endif

#define INVG 0.343100187f   // 1 / 2.9146

static __device__ __forceinline__ unsigned pack_h2(float a, float b) {
    return __builtin_bit_cast(unsigned, __builtin_amdgcn_cvt_pkrtz(a, b));
}
static __device__ __forceinline__ half2_t h2(unsigned u) {
    return __builtin_bit_cast(half2_t, u);
}
// acc += y . x over the 2 fp16 lanes (v_dot2_f32_f16)
static __device__ __forceinline__ float dot2p(unsigned y, half2_t x, float acc) {
#if HAVE_FDOT2
    return __builtin_amdgcn_fdot2(h2(y), x, acc, false);
#else
    half2_t yv = h2(y);
    acc = __builtin_fmaf((float)yv.x, (float)x.x, acc);
    acc = __builtin_fmaf((float)yv.y, (float)x.y, acc);
    return acc;
#endif
}
static __device__ __forceinline__ float dot2s(unsigned y, unsigned x, float acc) {
    return dot2p(y, h2(x), acc);
}

__global__ __launch_bounds__(NTHREADS, 8) void statden_kernel(
    const float* __restrict__ noisy, const float* __restrict__ guidance,
    const float* __restrict__ est, const float* __restrict__ var,
    const float* __restrict__ sigma_inv, float* __restrict__ out)
{
    extern __shared__ unsigned char smem[];
    unsigned* agP  = (unsigned*)smem;
    unsigned* evnP = agP + EVN_OFF;
    unsigned* x2P  = agP + X2_OFF;

    const int tid = threadIdx.x;
    const int pix = tid & (NCOL - 1);
    const int sub = tid >> 9;            // 2-way checkerboard split (8-wave-uniform)
    const int h0 = blockIdx.y * TH;
    const int w0 = blockIdx.x * TW;
    const int t0 = blockIdx.z * TT;

    float sq[9];
    #pragma unroll
    for (int c = 0; c < 9; ++c) sq[c] = sqrtf(sigma_inv[c] * LOG2E_SC);

    // ---- stage halo (zero-fill OOB == reference zero padding) ----
    for (int p = tid; p < NPX; p += NTHREADS) {
        int row = p / TSZ;
        int t   = p - row * TSZ;
        int pw  = row % WS;
        int ph  = row / WS;
        int h = h0 - SRAD + ph;
        int w = w0 - SRAD + pw;
        int tg = t0 - TRAD + t;
        bool ok = ((unsigned)h < (unsigned)Hdim) && ((unsigned)w < (unsigned)Wdim)
               && ((unsigned)tg < (unsigned)Tdim);
        int base = (h * Wdim + w) * Tdim + tg;

        float g[9];
        #pragma unroll
        for (int c = 0; c < 9; ++c) g[c] = ok ? guidance[c*CS + base] * sq[c] : 0.f;
        float e0 = ok ? est[0*CS + base] * INVG : 0.f;
        float e1 = ok ? est[1*CS + base] * INVG : 0.f;
        float e2 = ok ? est[2*CS + base] * INVG : 0.f;
        float v0 = ok ? var[0*CS + base] : 0.f;
        float v1 = ok ? var[1*CS + base] : 0.f;
        float v2 = ok ? var[2*CS + base] : 0.f;
        float n0 = ok ? noisy[0*CS + base] : 0.f;
        float n1 = ok ? noisy[1*CS + base] : 0.f;
        float n2 = ok ? noisy[2*CS + base] : 0.f;

        // slot index == linear p (RS == TSZ, no padding)
        uint4 ag;
        ag.x = pack_h2(g[0], g[1]); ag.y = pack_h2(g[2], g[3]);
        ag.z = pack_h2(g[4], g[5]); ag.w = pack_h2(g[6], g[7]);
        *(uint4*)(agP + 4*p) = ag;
        uint4 ev;
        ev.x = pack_h2(e0, e1); ev.y = pack_h2(v0, v1);
        ev.z = pack_h2(e2, v2); ev.w = pack_h2(n0, n1);
        *(uint4*)(evnP + 4*p) = ev;
        unsigned xq = pack_h2(g[8], n2);
        // S from PACKED values, identical chain order as eval dot -> center dist == 0
        half2_t x8 = h2(xq);
        float S = __builtin_fmaf((float)x8.x, (float)x8.x, 0.f);
        S = dot2s(ag.x, ag.x, S);
        S = dot2s(ag.y, ag.y, S);
        S = dot2s(ag.z, ag.z, S);
        S = dot2s(ag.w, ag.w, S);
        uint2 x2; x2.x = xq; x2.y = __builtin_bit_cast(unsigned, S);
        *(uint2*)(x2P + 2*p) = x2;
    }
    __syncthreads();

    // ---- per-thread single output px ----
    const int tt = pix & 7;
    const int ww = (pix >> 3) & 7;
    const int hh = pix >> 6;
    const int crow = (hh + SRAD) * WS + (ww + SRAD);
    const int cidx = crow * RS + tt;    // window slot for tp=0 (dt=-1)

    // center terms (center lives at slot cidx+1)
    half2_t agx0, agx1, agx2, agx3;
    float cgxf, Sx;
    half2_t ex01, vx01, cx2m;
    {
        const int ci = cidx + 1;
        uint4 cag = *(const uint4*)(agP + 4*ci);
        agx0 = h2(cag.x); agx1 = h2(cag.y);
        agx2 = h2(cag.z); agx3 = h2(cag.w);
        uint2 cx2 = *(const uint2*)(x2P + 2*ci);
        cgxf = (float)h2(cx2.x).x;
        Sx   = __builtin_bit_cast(float, cx2.y);
        uint4 cev = *(const uint4*)(evnP + 4*ci);
        ex01 = h2(cev.x);
        vx01 = h2(cev.y);
        cx2m = h2(cev.z ^ 0x00008000u);   // negate e2'
    }

    float nm0 = 0.f, nm1 = 0.f, nm2 = 0.f, den = 0.f;

    #pragma unroll 1
    for (int dh = 0; dh < 7; ++dh) {
        #pragma unroll 1
        for (int dw = ((dh + sub) & 1); dw < 7; dw += 2) {
            const int nbase = cidx + ((dh - SRAD) * WS + (dw - SRAD)) * RS;

            #pragma unroll
            for (int tp = 0; tp < 3; ++tp) {
                const int ni = nbase + tp;
                const uint4 a  = *(const uint4*)(agP + 4*ni);
                const uint2 x2 = *(const uint2*)(x2P + 2*ni);
                const float Sy = __builtin_bit_cast(float, x2.y);

                // guidance: nd = -(Sy + Sx - 2*dot)  (log2-scaled)
                float dot = __builtin_fmaf((float)h2(x2.x).x, cgxf, 0.f);
                dot = dot2p(a.x, agx0, dot);
                dot = dot2p(a.y, agx1, dot);
                dot = dot2p(a.z, agx2, dot);
                dot = dot2p(a.w, agx3, dot);
                const float ssum = Sy + Sx;
                const float nd = __builtin_fmaf(2.0f, dot, -ssum);   // = -dist

                // wave vote: any lane with non-negligible weight?
                const unsigned long long vote = __ballot(nd >= SKIP_ND);
                if (vote != 0ull) {
                    const uint4 e = *(const uint4*)(evnP + 4*ni);
                    const float wjf = EXPW(nd);

                    // packed t-test: vs - de^2 >= 0 per channel (e' = e/gamma)
                    const half2_t de01 = h2(e.x) - ex01;
                    const half2_t vs01 = h2(e.y) + vx01;
                    const half2_t m01  = PKFMA(-de01, de01, vs01);
                    const half2_t s2   = h2(e.z) + cx2m;
                    const _Float16 m2v = __builtin_fmaf16(-s2.x, s2.x, s2.y);
                    const _Float16 mn  = HMIN(HMIN(m01.x, m01.y), m2v);
                    const float wgt = (mn >= (_Float16)0) ? wjf : 0.f;

                    nm0 = __builtin_fmaf(wgt, (float)h2(e.w).x, nm0);
                    nm1 = __builtin_fmaf(wgt, (float)h2(e.w).y, nm1);
                    nm2 = __builtin_fmaf(wgt, (float)h2(x2.x).y, nm2);
                    den += wgt;
                }
            }
        }
    }

    // ---- combine 2 checkerboard partials via LDS ----
    __syncthreads();
    float* red = (float*)smem;   // 512 * 4 * 4 B = 8 KB, reuse staged region
    if (sub == 1) {
        float4 v; v.x = nm0; v.y = nm1; v.z = nm2; v.w = den;
        *(float4*)(red + 4 * pix) = v;
    }
    __syncthreads();
    if (sub == 0) {
        float4 v = *(const float4*)(red + 4 * pix);
        nm0 += v.x; nm1 += v.y; nm2 += v.z; den += v.w;
        const float inv = 1.0f / (den + 1e-10f);

        const int hG = h0 + hh, wG = w0 + ww;
        const int ob = (hG * Wdim + wG) * Tdim + t0 + tt;
        out[0*CS + ob] = nm0 * inv;
        out[1*CS + ob] = nm1 * inv;
        out[2*CS + ob] = nm2 * inv;
    }
}

extern "C" void kernel_launch(void* const* d_in, const int* in_sizes, int n_in,
                              void* d_out, int out_size, void* d_ws, size_t ws_size,
                              hipStream_t stream) {
    const float* noisy    = (const float*)d_in[0];
    const float* guidance = (const float*)d_in[1];
    const float* est      = (const float*)d_in[2];
    const float* var      = (const float*)d_in[3];
    const float* sig      = (const float*)d_in[4];
    float* out = (float*)d_out;

    (void)in_sizes; (void)n_in; (void)out_size; (void)d_ws; (void)ws_size;

    (void)hipFuncSetAttribute(reinterpret_cast<const void*>(statden_kernel),
                              hipFuncAttributeMaxDynamicSharedMemorySize, SMEM_BYTES);

    dim3 grid(Wdim / TW, Hdim / TH, Tdim / TT);   // (32, 32, 4)
    statden_kernel<<<grid, NTHREADS, SMEM_BYTES, stream>>>(noisy, guidance, est, var, sig, out);
}